// Round 5
// baseline (368.520 us; speedup 1.0000x reference)
//
#include <hip/hip_runtime.h>
#include <math.h>

// MotionGRU: B=4, N=4096, K=16, HID=128, FEAT=128
// ws layout (bytes):
//   H0tb bf16 [4][4096][128]      @ 0        (4 MB)
//   nn    int [4][4096][16]       @ 4 MB     (1 MB)
//   WmainP bf16 frags             @ 5 MB     (110592 B)
//   WfeP   bf16 frags             @ 5.5 MB   (98304 B)
//   WprP   bf16 frags             @ 5.75 MB  (32768 B)
//   P0p   f32x4 [4][4096]         @ 6 MB     (256 KB)
//   SmG   f32 [16384][512]        @ 8 MB     (32 MB)   cols: [R 0-127 | Z 128-255 | H0 256-383 | H1a 384-511]

#define BIGV 1e30f

typedef __attribute__((ext_vector_type(8))) short bf16x8;
typedef __attribute__((ext_vector_type(16))) float f32x16;

#define MFMA32(a, b, c) __builtin_amdgcn_mfma_f32_32x32x16_bf16(a, b, c, 0, 0, 0)

__device__ __forceinline__ unsigned short f2bf(float x) {
  unsigned int u = __float_as_uint(x);
  unsigned int r = u + 0x7fffu + ((u >> 16) & 1u);
  return (unsigned short)(r >> 16);
}
__device__ __forceinline__ float bf2f(unsigned short u) {
  return __uint_as_float(((unsigned int)u) << 16);
}

// ---------------- transpose H0 -> H0tb (64x64 tiles) + pack P0p ----------------
__global__ __launch_bounds__(256) void k_transpose(const float* __restrict__ H0,
                                                   unsigned short* __restrict__ H0tb,
                                                   const float* __restrict__ p0,
                                                   float4* __restrict__ P0p) {
  const int blk = blockIdx.x;
  if (blk >= 512) {  // pack candidates: P0p[b][j] = (x,y,z,|p|^2)
    int t = ((blk - 512) << 8) + threadIdx.x;   // 0..16383
    int b = t >> 12, j = t & 4095;
    const float* P0 = p0 + b * 3 * 4096;
    float x = P0[j], y = P0[4096 + j], z = P0[8192 + j];
    P0p[t] = make_float4(x, y, z, x * x + y * y + z * z);
    return;
  }
  __shared__ float tile[64][65];
  const int b = blk >> 7;
  const int rem = blk & 127;
  const int c0 = (rem >> 6) << 6;   // 0 or 64
  const int n0 = (rem & 63) << 6;
#pragma unroll
  for (int it = 0; it < 16; ++it) {
    int idx = (it << 8) + threadIdx.x;
    int r = idx >> 6, cl = idx & 63;
    tile[r][cl] = H0[((b << 7) + c0 + r) * 4096 + n0 + cl];
  }
  __syncthreads();
#pragma unroll
  for (int it = 0; it < 8; ++it) {
    int idx = (it << 8) + threadIdx.x;     // 0..2047
    int nr = idx >> 5, cc2 = (idx & 31) << 1;
    unsigned int v = (unsigned int)f2bf(tile[cc2][nr]) |
                     ((unsigned int)f2bf(tile[cc2 + 1][nr]) << 16);
    *(unsigned int*)&H0tb[((b << 12) + n0 + nr) * 128 + c0 + cc2] = v;
  }
}

// ---------------- exact KNN: 4 queries per wave ----------------
__device__ __forceinline__ unsigned long long knn_key(float v, int j) {
  unsigned int u = __float_as_uint(v);
  unsigned int mask = (unsigned int)(((int)u) >> 31) | 0x80000000u;
  return ((unsigned long long)(u ^ mask) << 32) | (unsigned int)j;
}

__global__ __launch_bounds__(256) void k_knn(const float4* __restrict__ P0p,
                                             const float* __restrict__ p1,
                                             int* __restrict__ nn) {
  const int wv = threadIdx.x >> 6, lane = threadIdx.x & 63;
  const int g0 = ((blockIdx.x << 2) + wv) << 2;    // first of 4 queries
  const int b = g0 >> 12, m0 = g0 & 4095;
  const float* P1 = p1 + b * 3 * 4096;
  float nx[4], ny[4], nz[4], s1[4];
#pragma unroll
  for (int q = 0; q < 4; ++q) {
    float x1 = P1[m0 + q], y1 = P1[4096 + m0 + q], z1 = P1[8192 + m0 + q];
    s1[q] = x1 * x1 + y1 * y1 + z1 * z1;
    nx[q] = -2.f * x1; ny[q] = -2.f * y1; nz[q] = -2.f * z1;
  }
  const float4* C = P0p + (b << 12);

  float v0[4], v1[4], v2[4], v3[4];
  int j0[4], j1[4], j2[4], j3[4];
#pragma unroll
  for (int q = 0; q < 4; ++q) {
    v0[q] = v1[q] = v2[q] = v3[q] = BIGV;
    j0[q] = j1[q] = j2[q] = j3[q] = 0;
  }
#pragma unroll 4
  for (int tt = 0; tt < 64; ++tt) {
    const int j = (tt << 6) + lane;
    float4 c = C[j];
#pragma unroll
    for (int q = 0; q < 4; ++q) {
      float sq = fmaf(nz[q], c.z, fmaf(ny[q], c.y, fmaf(nx[q], c.x, s1[q] + c.w)));
      bool c0_ = sq < v0[q], c1_ = sq < v1[q], c2_ = sq < v2[q], c3_ = sq < v3[q];
      j3[q] = c3_ ? (c2_ ? j2[q] : j) : j3[q];
      j2[q] = c2_ ? (c1_ ? j1[q] : j) : j2[q];
      j1[q] = c1_ ? (c0_ ? j0[q] : j) : j1[q];
      j0[q] = c0_ ? j : j0[q];
      v3[q] = __builtin_amdgcn_fmed3f(sq, v2[q], v3[q]);
      v2[q] = __builtin_amdgcn_fmed3f(sq, v1[q], v2[q]);
      v1[q] = __builtin_amdgcn_fmed3f(sq, v0[q], v1[q]);
      v0[q] = fminf(sq, v0[q]);
    }
  }

  const unsigned long long INFK = ~0ull;
  unsigned long long k0[4], k1[4], k2[4], k3[4], wkey[4], lastk[4];
#pragma unroll
  for (int q = 0; q < 4; ++q) {
    k0[q] = knn_key(v0[q], j0[q]); k1[q] = knn_key(v1[q], j1[q]);
    k2[q] = knn_key(v2[q], j2[q]); k3[q] = knn_key(v3[q], j3[q]);
    wkey[q] = 0; lastk[q] = 0;
  }
#pragma unroll 1
  for (int r = 0; r < 16; ++r) {
    unsigned long long mk[4];
#pragma unroll
    for (int q = 0; q < 4; ++q) {
      mk[q] = k0[q];
      if (__any((int)(k0[q] == INFK))) {
        // rare: a lane exhausted its 4 slots -> exact successor rescan
        if (k0[q] == INFK) {
          float x1 = P1[m0 + q], y1 = P1[4096 + m0 + q], z1 = P1[8192 + m0 + q];
          float s1q = x1 * x1 + y1 * y1 + z1 * z1;
          float nxq = -2.f * x1, nyq = -2.f * y1, nzq = -2.f * z1;
          unsigned long long best = INFK;
#pragma unroll 1
          for (int t2 = 0; t2 < 64; ++t2) {
            const int j = (t2 << 6) + lane;
            float4 c = C[j];
            float sq = fmaf(nzq, c.z, fmaf(nyq, c.y, fmaf(nxq, c.x, s1q + c.w)));
            unsigned long long kk = knn_key(sq, j);
            if (kk > lastk[q] && kk < best) best = kk;
          }
          mk[q] = best;
        }
      }
    }
    // wave-min butterflies, 4 chains interleaved
#pragma unroll
    for (int off = 1; off < 64; off <<= 1) {
#pragma unroll
      for (int q = 0; q < 4; ++q) {
        unsigned long long ok = __shfl_xor(mk[q], off);
        mk[q] = (ok < mk[q]) ? ok : mk[q];
      }
    }
#pragma unroll
    for (int q = 0; q < 4; ++q) {
      if (lane == r) wkey[q] = mk[q];
      lastk[q] = mk[q];
      if (k0[q] == mk[q]) { k0[q] = k1[q]; k1[q] = k2[q]; k2[q] = k3[q]; k3[q] = INFK; }
    }
  }
  if (lane < 16) {
#pragma unroll
    for (int q = 0; q < 4; ++q)
      nn[(((b << 12) + m0 + q) << 4) + lane] = (int)(unsigned int)wkey[q];
  }
}

// ---------------- pack weight fragments (one-time, tiny) ----------------
__global__ __launch_bounds__(256) void k_prep(const float* __restrict__ W_R,
                                              const float* __restrict__ W_Z,
                                              const float* __restrict__ W_H0,
                                              const float* __restrict__ W_H1,
                                              unsigned short* __restrict__ WmainP,
                                              unsigned short* __restrict__ WfeP,
                                              unsigned short* __restrict__ WprP) {
  int t = blockIdx.x * 256 + threadIdx.x;
  if (t < 6912) {  // 12 tiles * 9 ks * 64 lanes
    int l = t & 63;
    int f = t >> 6;
    int ks = f % 9, T = f / 9;
    int col = T * 32 + (l & 31);
    int kb = ks * 16 + ((l >> 5) << 3);
    const float* W; int stride, row;
    if (col < 128)      { W = W_R;  stride = 260; row = col; }
    else if (col < 256) { W = W_Z;  stride = 260; row = col - 128; }
    else                { W = W_H0; stride = 132; row = col - 256; }
    unsigned int u[4];
#pragma unroll
    for (int i2 = 0; i2 < 4; ++i2) {
      float a0, a1;
      int k0 = kb + 2 * i2, k1 = k0 + 1;
      a0 = (k0 < 128) ? W[row * stride + 4 + k0] : ((k0 < 132) ? W[row * stride + (k0 - 128)] : 0.f);
      a1 = (k1 < 128) ? W[row * stride + 4 + k1] : ((k1 < 132) ? W[row * stride + (k1 - 128)] : 0.f);
      u[i2] = (unsigned int)f2bf(a0) | ((unsigned int)f2bf(a1) << 16);
    }
    uint4 pk; pk.x = u[0]; pk.y = u[1]; pk.z = u[2]; pk.w = u[3];
    *(uint4*)&WmainP[t * 8] = pk;
  } else if (t < 13056) {  // 12 tiles * 8 ks * 64 lanes
    int idx = t - 6912;
    int l = idx & 63;
    int ks = (idx >> 6) & 7;
    int tid = idx >> 9;
    int kb = ks * 16 + ((l >> 5) << 3);
    unsigned int u[4];
#pragma unroll
    for (int i2 = 0; i2 < 4; ++i2) {
      int k0 = kb + 2 * i2, k1 = k0 + 1;
      float a0, a1;
      if (tid < 8) {
        int col = tid * 32 + (l & 31);
        const float* W = (col < 128) ? W_R : W_Z;
        int row = (col < 128) ? col : col - 128;
        a0 = W[row * 260 + 132 + k0];
        a1 = W[row * 260 + 132 + k1];
      } else {
        int row = (tid - 8) * 32 + (l & 31);
        a0 = W_H1[row * 256 + k0];
        a1 = W_H1[row * 256 + k1];
      }
      u[i2] = (unsigned int)f2bf(a0) | ((unsigned int)f2bf(a1) << 16);
    }
    uint4 pk; pk.x = u[0]; pk.y = u[1]; pk.z = u[2]; pk.w = u[3];
    *(uint4*)&WfeP[idx * 8] = pk;
  } else if (t < 15104) {  // W_H1[:,128:256] B-frags: 4 tiles * 8 ks * 64 lanes
    int idx = t - 13056;
    int l = idx & 63;
    int ks = (idx >> 6) & 7;
    int T = idx >> 9;                  // 0..3
    int row = T * 32 + (l & 31);
    int kb = ks * 16 + ((l >> 5) << 3);
    unsigned int u[4];
#pragma unroll
    for (int i2 = 0; i2 < 4; ++i2) {
      int k0 = kb + 2 * i2;
      float a0 = W_H1[row * 256 + 128 + k0];
      float a1 = W_H1[row * 256 + 128 + k0 + 1];
      u[i2] = (unsigned int)f2bf(a0) | ((unsigned int)f2bf(a1) << 16);
    }
    uint4 pk; pk.x = u[0]; pk.y = u[1]; pk.z = u[2]; pk.w = u[3];
    *(uint4*)&WprP[idx * 8] = pk;
  }
}

// ---------------- main MFMA kernel (unchanged from round 3) ----------------
__global__ __launch_bounds__(256, 2) void k_mainmax(
    const unsigned short* __restrict__ H0tb, const int* __restrict__ nn,
    const float* __restrict__ p0, const float* __restrict__ p1,
    const float* __restrict__ ct, const float* __restrict__ mo,
    const short* __restrict__ WmainP, const short* __restrict__ WfeP,
    float* __restrict__ SmG) {
  __shared__ unsigned short Xb[2][18][32][8];
  __shared__ unsigned short FeL[16][32][8];

  const int t = threadIdx.x;
  const int g = blockIdx.x;
  const int b = g >> 7;
  const int n0 = (g & 127) << 5;
  const int w = t >> 6, lane = t & 63;
  const int l31 = lane & 31, h = lane >> 5;

  bf16x8 wfm[3][9];
#pragma unroll
  for (int tt = 0; tt < 3; ++tt)
#pragma unroll
    for (int ks = 0; ks < 9; ++ks)
      wfm[tt][ks] = *(const bf16x8*)&WmainP[(((3 * w + tt) * 9 + ks) * 64 + lane) * 8];

  auto stageX = [&](int buf, int pi) {
    int s = t >> 3, c = t & 7;
    int n = n0 + pi + ((s >> 4) << 4);
    int j = nn[(((b << 12) + n) << 4) + (s & 15)];
    const uint4* src = (const uint4*)&H0tb[((b << 12) + j) * 128];
    *(uint4*)&Xb[buf][c][s][0]     = src[c];
    *(uint4*)&Xb[buf][c + 8][s][0] = src[c + 8];
    if (t < 32) {
      int s2 = t;
      int n2 = n0 + pi + ((s2 >> 4) << 4);
      int j2 = nn[(((b << 12) + n2) << 4) + (s2 & 15)];
      const float* P1b = p1 + b * 3 * 4096;
      const float* P0b = p0 + b * 3 * 4096;
      float rx = P0b[j2] - P1b[n2];
      float ry = P0b[4096 + j2] - P1b[4096 + n2];
      float rz = P0b[8192 + j2] - P1b[8192 + n2];
      float dd = sqrtf(rx * rx + ry * ry + rz * rz);
      uint4 pk;
      pk.x = (unsigned int)f2bf(rx) | ((unsigned int)f2bf(ry) << 16);
      pk.y = (unsigned int)f2bf(rz) | ((unsigned int)f2bf(dd) << 16);
      pk.z = 0u; pk.w = 0u;
      *(uint4*)&Xb[buf][16][s2][0] = pk;
      uint4 z; z.x = 0u; z.y = 0u; z.z = 0u; z.w = 0u;
      *(uint4*)&Xb[buf][17][s2][0] = z;
    }
  };

  {
    int s = t >> 3, kg = t & 7;
    int n = n0 + s;
#pragma unroll
    for (int half = 0; half < 2; ++half) {
      int kgg = kg + 8 * half;
      const float* src = half ? (mo + b * 64 * 4096) : (ct + b * 64 * 4096);
      int ch = kg * 8;
      unsigned int u[4];
#pragma unroll
      for (int i2 = 0; i2 < 4; ++i2) {
        float a0 = src[(ch + 2 * i2) * 4096 + n];
        float a1 = src[(ch + 2 * i2 + 1) * 4096 + n];
        u[i2] = (unsigned int)f2bf(a0) | ((unsigned int)f2bf(a1) << 16);
      }
      uint4 pk; pk.x = u[0]; pk.y = u[1]; pk.z = u[2]; pk.w = u[3];
      *(uint4*)&FeL[kgg][s][0] = pk;
    }
  }
  stageX(0, 0);
  __syncthreads();

  float accF[3][16];
#pragma unroll
  for (int tt = 0; tt < 3; ++tt)
#pragma unroll
    for (int r = 0; r < 16; ++r) accF[tt][r] = 0.f;

  bf16x8 fe[8];
#pragma unroll
  for (int ks = 0; ks < 8; ++ks) fe[ks] = *(const bf16x8*)&FeL[2 * ks + h][l31][0];

#pragma unroll
  for (int tt = 0; tt < 3; ++tt) {
    if (3 * w + tt < 8) {
      f32x16 a;
#pragma unroll
      for (int r = 0; r < 16; ++r) a[r] = 0.f;
#pragma unroll
      for (int ks = 0; ks < 8; ++ks) {
        bf16x8 wf = *(const bf16x8*)&WfeP[(((3 * w + tt) * 8 + ks) * 64 + lane) * 8];
        a = MFMA32(fe[ks], wf, a);
      }
#pragma unroll
      for (int r = 0; r < 16; ++r) accF[tt][r] = a[r];
    }
  }

#pragma unroll
  for (int pi = 0; pi < 16; ++pi) {
    if (pi < 15) stageX((pi + 1) & 1, pi + 1);

    f32x16 a0, a1, a2;
#pragma unroll
    for (int r = 0; r < 16; ++r) { a0[r] = 0.f; a1[r] = 0.f; a2[r] = 0.f; }
#pragma unroll
    for (int ks = 0; ks < 9; ++ks) {
      bf16x8 xf = *(const bf16x8*)&Xb[pi & 1][2 * ks + h][l31][0];
      a0 = MFMA32(xf, wfm[0][ks], a0);
      a1 = MFMA32(xf, wfm[1][ks], a1);
      a2 = MFMA32(xf, wfm[2][ks], a2);
    }

    const int ra = (pi & 3) + (((pi >> 3) & 1) << 2);
    const int ha = (pi >> 2) & 1;
    const bool sel = (h == ha);
#pragma unroll
    for (int tt = 0; tt < 3; ++tt) {
      const f32x16& a = (tt == 0) ? a0 : ((tt == 1) ? a1 : a2);
      float ma = fmaxf(fmaxf(fmaxf(a[0], a[1]), fmaxf(a[2], a[3])),
                       fmaxf(fmaxf(a[4], a[5]), fmaxf(a[6], a[7])));
      float mb = fmaxf(fmaxf(fmaxf(a[8], a[9]), fmaxf(a[10], a[11])),
                       fmaxf(fmaxf(a[12], a[13]), fmaxf(a[14], a[15])));
      ma = fmaxf(ma, __shfl_xor(ma, 32));
      mb = fmaxf(mb, __shfl_xor(mb, 32));
      accF[tt][ra]     += sel ? ma : 0.f;
      accF[tt][ra + 8] += sel ? mb : 0.f;
    }
    __syncthreads();
  }

  const long base = (long)(g << 5) * 512;
#pragma unroll
  for (int tt = 0; tt < 3; ++tt)
#pragma unroll
    for (int r = 0; r < 16; ++r) {
      int pt = (r & 3) + ((r >> 2) << 3) + 4 * h;
      SmG[base + (long)pt * 512 + 96 * w + 32 * tt + l31] = accF[tt][r];
    }

  {
    f32x16 a;
#pragma unroll
    for (int r = 0; r < 16; ++r) a[r] = 0.f;
#pragma unroll
    for (int ks = 0; ks < 8; ++ks) {
      bf16x8 feq = *(const bf16x8*)&FeL[2 * ks + h][l31][0];
      bf16x8 wf = *(const bf16x8*)&WfeP[(((8 + w) * 8 + ks) * 64 + lane) * 8];
      a = MFMA32(feq, wf, a);
    }
#pragma unroll
    for (int r = 0; r < 16; ++r) {
      int pt = (r & 3) + ((r >> 2) << 3) + 4 * h;
      SmG[base + (long)pt * 512 + 384 + 32 * w + l31] = a[r];
    }
  }
}

// ---------------- MFMA epilogue: Pr hi/lo GEMM + gates + tanh + store ----------------
// block = 256 thr (4 waves), 64 points. XOR-swizzled PrH in LDS.
__device__ __forceinline__ int prh_idx(int hl, int pt, int c) {
  int blkc = (c >> 3) ^ (pt & 15);
  return hl * 8192 + pt * 128 + blkc * 8 + (c & 7);
}

__global__ __launch_bounds__(256) void k_epi2(
    const float* __restrict__ SmG, const short* __restrict__ WprP,
    const float* __restrict__ b_R, const float* __restrict__ b_Z,
    const float* __restrict__ b_H0, const float* __restrict__ b_H1,
    float* __restrict__ out) {
  __shared__ __align__(16) float lds[64 * 132];   // 33792 B; aliased PrH (32KB) then Ot
  unsigned short* PrH = (unsigned short*)lds;
  const int t = threadIdx.x;
  const int blk = blockIdx.x;
  const long gp0 = (long)blk * 64;
  const int b = (int)(gp0 >> 12);
  const int nb = (int)(gp0 & 4095);
  const int w = t >> 6, lane = t & 63, l31 = lane & 31, h = lane >> 5;

  // Phase A: Pr = sigmoid(R+bR)*(H0+bH0), split hi/lo bf16, swizzled into LDS
  {
    const int pt = t >> 2, cg = (t & 3) << 5;
    const float* row = SmG + (gp0 + pt) * 512;
#pragma unroll
    for (int i = 0; i < 8; ++i) {
      int c = cg + (i << 2);
      float4 Rv = *(const float4*)&row[c];
      float4 Hv = *(const float4*)&row[256 + c];
      float4 br = *(const float4*)&b_R[c];
      float4 bh = *(const float4*)&b_H0[c];
      float pr0 = (Hv.x + bh.x) / (1.f + __expf(-(Rv.x + br.x)));
      float pr1 = (Hv.y + bh.y) / (1.f + __expf(-(Rv.y + br.y)));
      float pr2 = (Hv.z + bh.z) / (1.f + __expf(-(Rv.z + br.z)));
      float pr3 = (Hv.w + bh.w) / (1.f + __expf(-(Rv.w + br.w)));
      unsigned short h0s = f2bf(pr0), h1s = f2bf(pr1), h2s = f2bf(pr2), h3s = f2bf(pr3);
      unsigned short l0s = f2bf(pr0 - bf2f(h0s)), l1s = f2bf(pr1 - bf2f(h1s));
      unsigned short l2s = f2bf(pr2 - bf2f(h2s)), l3s = f2bf(pr3 - bf2f(h3s));
      *(uint2*)&PrH[prh_idx(0, pt, c)] =
          make_uint2((unsigned int)h0s | ((unsigned int)h1s << 16),
                     (unsigned int)h2s | ((unsigned int)h3s << 16));
      *(uint2*)&PrH[prh_idx(1, pt, c)] =
          make_uint2((unsigned int)l0s | ((unsigned int)l1s << 16),
                     (unsigned int)l2s | ((unsigned int)l3s << 16));
    }
  }
  __syncthreads();

  // Phase B: hB[pt][r] via MFMA, wave w owns rows 32w..32w+31
  f32x16 ac0, ac1;
#pragma unroll
  for (int r = 0; r < 16; ++r) { ac0[r] = 0.f; ac1[r] = 0.f; }
#pragma unroll
  for (int ks = 0; ks < 8; ++ks) {
    bf16x8 wf = *(const bf16x8*)&WprP[((w * 8 + ks) * 64 + lane) * 8];
    int cb = ks * 16 + (h << 3);
    bf16x8 a0h = *(const bf16x8*)&PrH[prh_idx(0, l31, cb)];
    bf16x8 a0l = *(const bf16x8*)&PrH[prh_idx(1, l31, cb)];
    bf16x8 a1h = *(const bf16x8*)&PrH[prh_idx(0, 32 + l31, cb)];
    bf16x8 a1l = *(const bf16x8*)&PrH[prh_idx(1, 32 + l31, cb)];
    ac0 = MFMA32(a0h, wf, ac0);
    ac0 = MFMA32(a0l, wf, ac0);
    ac1 = MFMA32(a1h, wf, ac1);
    ac1 = MFMA32(a1l, wf, ac1);
  }
  __syncthreads();   // PrH reads done; lds becomes Ot

  // Phase C: combine + Ot[pt][132 + r-slot layout: Ot[pt*132 + r]]
  float* Ot = lds;
  const int rglob = (w << 5) + l31;
  const float bZr = b_Z[rglob], bH0r = b_H0[rglob], bH1r = b_H1[rglob];
#pragma unroll
  for (int pt_t = 0; pt_t < 2; ++pt_t) {
#pragma unroll
    for (int r = 0; r < 16; ++r) {
      float hBv = pt_t ? ac1[r] : ac0[r];
      int pt = (pt_t << 5) + (r & 3) + ((r >> 2) << 3) + (h << 2);
      const float* prow = SmG + (gp0 + pt) * 512;
      float Z   = prow[128 + rglob];
      float H0v = prow[256 + rglob];
      float Aa  = prow[384 + rglob];
      float gZ = 1.f / (1.f + __expf(-(Z + bZr)));
      float h0 = H0v + bH0r;
      float h1 = tanhf(Aa + hBv + bH1r);
      Ot[pt * 132 + rglob] = gZ * h0 + (1.f - gZ) * h1;
    }
  }
  __syncthreads();

  // store: thread -> row rr, half of the 64 points; gather from Ot, coalesced f4 stores
  {
    const int rr = t >> 1, half = t & 1;
#pragma unroll
    for (int qq = 0; qq < 8; ++qq) {
      int pb = (half << 5) + (qq << 2);
      float4 v;
      v.x = Ot[(pb + 0) * 132 + rr];
      v.y = Ot[(pb + 1) * 132 + rr];
      v.z = Ot[(pb + 2) * 132 + rr];
      v.w = Ot[(pb + 3) * 132 + rr];
      *(float4*)&out[(long)((b << 7) + rr) * 4096 + nb + pb] = v;
    }
  }
}

extern "C" void kernel_launch(void* const* d_in, const int* in_sizes, int n_in,
                              void* d_out, int out_size, void* d_ws, size_t ws_size,
                              hipStream_t stream) {
  const float* H0  = (const float*)d_in[0];
  const float* p0  = (const float*)d_in[1];
  const float* p1  = (const float*)d_in[2];
  const float* ct  = (const float*)d_in[3];
  const float* mo  = (const float*)d_in[4];
  const float* W_R = (const float*)d_in[5];
  const float* b_R = (const float*)d_in[6];
  const float* W_Z = (const float*)d_in[7];
  const float* b_Z = (const float*)d_in[8];
  const float* W_H0 = (const float*)d_in[9];
  const float* b_H0 = (const float*)d_in[10];
  const float* W_H1 = (const float*)d_in[11];
  const float* b_H1 = (const float*)d_in[12];
  float* out = (float*)d_out;

  unsigned short* H0tb   = (unsigned short*)d_ws;
  int* nn                = (int*)((char*)d_ws + 4ull * 1024 * 1024);
  unsigned short* WmainP = (unsigned short*)((char*)d_ws + 5ull * 1024 * 1024);
  unsigned short* WfeP   = (unsigned short*)((char*)d_ws + 5ull * 1024 * 1024 + 512ull * 1024);
  unsigned short* WprP   = (unsigned short*)((char*)d_ws + 5ull * 1024 * 1024 + 768ull * 1024);
  float4* P0p            = (float4*)((char*)d_ws + 6ull * 1024 * 1024);
  float* SmG             = (float*)((char*)d_ws + 8ull * 1024 * 1024);

  k_transpose<<<576, 256, 0, stream>>>(H0, H0tb, p0, P0p);
  k_knn<<<1024, 256, 0, stream>>>(P0p, p1, nn);
  k_prep<<<59, 256, 0, stream>>>(W_R, W_Z, W_H0, W_H1, WmainP, WfeP, WprP);
  k_mainmax<<<512, 256, 0, stream>>>(H0tb, nn, p0, p1, ct, mo,
                                     (const short*)WmainP, (const short*)WfeP, SmG);
  k_epi2<<<256, 256, 0, stream>>>(SmG, (const short*)WprP, b_R, b_Z, b_H0, b_H1, out);
}